// Round 7
// baseline (114.018 us; speedup 1.0000x reference)
//
#include <hip/hip_runtime.h>
#include <math.h>

typedef __bf16 bf16x8 __attribute__((ext_vector_type(8)));
typedef float  f32x4  __attribute__((ext_vector_type(4)));
typedef float  vf4    __attribute__((ext_vector_type(4)));   // native vec for NT builtins

__device__ __forceinline__ float wave_sum(float v) {
#pragma unroll
    for (int m = 1; m < 64; m <<= 1) v += __shfl_xor(v, m, 64);
    return v;
}

__device__ __forceinline__ unsigned short f2bf(float f) {
    union { float f; unsigned int u; } x; x.f = f;
    unsigned int u = x.u;
    u += 0x7fffu + ((u >> 16) & 1u);   // round-to-nearest-even
    return (unsigned short)(u >> 16);
}
__device__ __forceinline__ float bf2f(unsigned short h) {
    union { unsigned int u; float f; } x; x.u = ((unsigned int)h) << 16;
    return x.f;
}

// streaming (non-temporal) access helpers: keep L2 free for weight tiles
__device__ __forceinline__ float4 ntload4(const float* p) {
    const vf4 v = __builtin_nontemporal_load((const vf4*)p);
    return make_float4(v.x, v.y, v.z, v.w);
}
__device__ __forceinline__ void ntstore(float* p, float v) {
    __builtin_nontemporal_store(v, p);
}

// ------- weight transpose/convert: W[c][n] f32 -> Wt_hi/lo[n][c] bf16 ------
__global__ __launch_bounds__(256) void k_wconv(
    const float* __restrict__ w_qc, const float* __restrict__ w_k,
    const float* __restrict__ w_v, const float* __restrict__ w_qf,
    unsigned short* __restrict__ Wt_hi, unsigned short* __restrict__ Wt_lo,
    unsigned short* __restrict__ Wtq_hi, unsigned short* __restrict__ Wtq_lo)
{
    __shared__ float T[64][65];
    const int tid = threadIdx.x;
    const int bid = blockIdx.x;
    const float* src; int width, col0, n0, ct, dpitch;
    unsigned short *dhi, *dlo;
    if (bid < 48) {
        const int nt = bid >> 3; ct = bid & 7;
        n0 = nt * 64;
        if (n0 < 64)       { src = w_qc; col0 = n0;       width = 64;  }
        else if (n0 < 128) { src = w_k;  col0 = n0 - 64;  width = 64;  }
        else               { src = w_v;  col0 = n0 - 128; width = 256; }
        dhi = Wt_hi; dlo = Wt_lo; dpitch = 512;
    } else {
        ct = bid - 48; n0 = 0; src = w_qf; col0 = 0; width = 64;
        dhi = Wtq_hi; dlo = Wtq_lo; dpitch = 256;
    }
    const int rl = tid >> 6, nl = tid & 63;
    for (int r = rl; r < 64; r += 4)
        T[r][nl] = src[(size_t)(ct * 64 + r) * width + col0 + nl];
    __syncthreads();
    for (int nr = rl; nr < 64; nr += 4) {
        const float w = T[nl][nr];
        const unsigned short h = f2bf(w);
        dhi[(size_t)(n0 + nr) * dpitch + ct * 64 + nl] = h;
        dlo[(size_t)(n0 + nr) * dpitch + ct * 64 + nl] = f2bf(w - bf2f(h));
    }
}

// ---------------- Kernel 1: fused coarse LN + gate + MFMA GEMM -------------
// 512 threads (8 waves), M=32 px/block, K=512, N=384.
#define AP 520
__global__ __launch_bounds__(512) void k_coarse_fused(
    const float* __restrict__ coarse,
    const float* __restrict__ ln_g, const float* __restrict__ ln_b,
    const float* __restrict__ w_gate, const float* __restrict__ b_gate,
    const unsigned short* __restrict__ Wt_hi,
    const unsigned short* __restrict__ Wt_lo,
    const float* __restrict__ b_qc, const float* __restrict__ b_k,
    const float* __restrict__ b_v,
    float* __restrict__ gate_o, float* __restrict__ qc_o,
    float* __restrict__ key_o, float* __restrict__ val_o)
{
    __shared__ unsigned short Ah[32 * AP];   // 33280 B
    __shared__ unsigned short Al[32 * AP];   // 33280 B  -> 2 blocks/CU
    const int tid = threadIdx.x;
    const int lane = tid & 63, wave = tid >> 6;
    const int ci0 = blockIdx.x << 5;

    // --- LN phase: wave w handles pixels 4w..4w+3 (NT loads: streaming) ---
    for (int pp = 0; pp < 4; ++pp) {
        const int p = (wave << 2) + pp;
        const float* src = coarse + (size_t)(ci0 + p) * 512;
        const int c0 = lane * 4, c1 = 256 + lane * 4;
        const float4 x0 = ntload4(src + c0);
        const float4 x1 = ntload4(src + c1);
        float s = (x0.x + x0.y) + (x0.z + x0.w) + (x1.x + x1.y) + (x1.z + x1.w);
        float sq = x0.x*x0.x + x0.y*x0.y + x0.z*x0.z + x0.w*x0.w
                 + x1.x*x1.x + x1.y*x1.y + x1.z*x1.z + x1.w*x1.w;
        s = wave_sum(s); sq = wave_sum(sq);
        const float mean = s * (1.0f / 512.0f);
        const float var  = sq * (1.0f / 512.0f) - mean * mean;
        const float inv  = rsqrtf(var + 1e-3f);
        const float4 g0 = *(const float4*)(ln_g + c0), g1 = *(const float4*)(ln_g + c1);
        const float4 h0 = *(const float4*)(ln_b + c0), h1 = *(const float4*)(ln_b + c1);
        float y[8];
        y[0] = (x0.x - mean) * inv * g0.x + h0.x;
        y[1] = (x0.y - mean) * inv * g0.y + h0.y;
        y[2] = (x0.z - mean) * inv * g0.z + h0.z;
        y[3] = (x0.w - mean) * inv * g0.w + h0.w;
        y[4] = (x1.x - mean) * inv * g1.x + h1.x;
        y[5] = (x1.y - mean) * inv * g1.y + h1.y;
        y[6] = (x1.z - mean) * inv * g1.z + h1.z;
        y[7] = (x1.w - mean) * inv * g1.w + h1.w;
        unsigned short* ah = Ah + p * AP;
        unsigned short* al = Al + p * AP;
#pragma unroll
        for (int j = 0; j < 8; ++j) {
            const int c = (j < 4) ? (c0 + j) : (c1 + j - 4);
            const unsigned short h = f2bf(y[j]);
            ah[c] = h;
            al[c] = f2bf(y[j] - bf2f(h));
        }
        const float4 wg0 = *(const float4*)(w_gate + c0), wg1 = *(const float4*)(w_gate + c1);
        float gd = y[0]*wg0.x + y[1]*wg0.y + y[2]*wg0.z + y[3]*wg0.w
                 + y[4]*wg1.x + y[5]*wg1.y + y[6]*wg1.z + y[7]*wg1.w;
        gd = wave_sum(gd);
        if (lane == 0) ntstore(gate_o + ci0 + p, 1.0f / (1.0f + __expf(-(gd + b_gate[0]))));
    }
    __syncthreads();

    // --- GEMM: per wave 1 split n-frag (3 MFMA) + 2 value n-frags ---
    const int lrow = lane & 15, m16 = lane & 15, lk = (lane >> 4) * 8;
    f32x4 acc_s[2], acc_v[2][2];
#pragma unroll
    for (int i = 0; i < 2; ++i) {
        acc_s[i] = (f32x4){0.f, 0.f, 0.f, 0.f};
        acc_v[i][0] = (f32x4){0.f, 0.f, 0.f, 0.f};
        acc_v[i][1] = (f32x4){0.f, 0.f, 0.f, 0.f};
    }

    const unsigned short* Bs_h = Wt_hi + (size_t)(wave * 16 + lrow) * 512 + lk;
    const unsigned short* Bs_l = Wt_lo + (size_t)(wave * 16 + lrow) * 512 + lk;
    const unsigned short* Bv0  = Wt_hi + (size_t)(128 + wave * 32 + lrow) * 512 + lk;
    const unsigned short* Bv1  = Wt_hi + (size_t)(128 + wave * 32 + 16 + lrow) * 512 + lk;

    // depth-2 register prefetch (all indices compile-time after full unroll)
    bf16x8 pbh[2], pbl[2], pv0[2], pv1[2];
#pragma unroll
    for (int i = 0; i < 2; ++i) {
        pbh[i] = *(const bf16x8*)(Bs_h + i * 32);
        pbl[i] = *(const bf16x8*)(Bs_l + i * 32);
        pv0[i] = *(const bf16x8*)(Bv0 + i * 32);
        pv1[i] = *(const bf16x8*)(Bv1 + i * 32);
    }

#pragma unroll
    for (int kk = 0; kk < 16; ++kk) {
        const int cur = kk & 1;
        const bf16x8 bh = pbh[cur], bl = pbl[cur], v0 = pv0[cur], v1 = pv1[cur];
        if (kk < 14) {
            pbh[cur] = *(const bf16x8*)(Bs_h + (kk + 2) * 32);
            pbl[cur] = *(const bf16x8*)(Bs_l + (kk + 2) * 32);
            pv0[cur] = *(const bf16x8*)(Bv0 + (kk + 2) * 32);
            pv1[cur] = *(const bf16x8*)(Bv1 + (kk + 2) * 32);
        }
        bf16x8 ah[2], alo[2];
#pragma unroll
        for (int mf = 0; mf < 2; ++mf) {
            ah[mf]  = *(const bf16x8*)&Ah[(mf * 16 + lrow) * AP + kk * 32 + lk];
            alo[mf] = *(const bf16x8*)&Al[(mf * 16 + lrow) * AP + kk * 32 + lk];
        }
#pragma unroll
        for (int mf = 0; mf < 2; ++mf) {
            acc_s[mf] = __builtin_amdgcn_mfma_f32_16x16x32_bf16(ah[mf],  bh, acc_s[mf], 0, 0, 0);
            acc_s[mf] = __builtin_amdgcn_mfma_f32_16x16x32_bf16(alo[mf], bh, acc_s[mf], 0, 0, 0);
            acc_s[mf] = __builtin_amdgcn_mfma_f32_16x16x32_bf16(ah[mf],  bl, acc_s[mf], 0, 0, 0);
            acc_v[mf][0] = __builtin_amdgcn_mfma_f32_16x16x32_bf16(ah[mf], v0, acc_v[mf][0], 0, 0, 0);
            acc_v[mf][1] = __builtin_amdgcn_mfma_f32_16x16x32_bf16(ah[mf], v1, acc_v[mf][1], 0, 0, 0);
        }
    }

    // --- epilogue (NT stores: streaming) ---
    const int rbase = (lane >> 4) * 4;
    const int ns = wave * 16 + m16;
#pragma unroll
    for (int mf = 0; mf < 2; ++mf) {
#pragma unroll
        for (int r = 0; r < 4; ++r) {
            const int m = mf * 16 + rbase + r;
            const int ci = ci0 + m;
            const float vs = acc_s[mf][r];
            if (ns < 64) ntstore(qc_o  + (size_t)ci * 64 + ns,      vs + b_qc[ns]);
            else         ntstore(key_o + (size_t)ci * 64 + ns - 64, vs + b_k[ns - 64]);
#pragma unroll
            for (int vv = 0; vv < 2; ++vv) {
                const int ch = wave * 32 + vv * 16 + m16;
                ntstore(val_o + (size_t)ci * 256 + ch, acc_v[mf][vv][r] + b_v[ch]);
            }
        }
    }
}

// ---------------- Kernel 2: fused fine LN + split-bf16 qf + gating ---------
#define QP 264
__global__ __launch_bounds__(256) void k_query_fused(
    const float* __restrict__ fine,
    const float* __restrict__ ln_g, const float* __restrict__ ln_b,
    const unsigned short* __restrict__ Wtq_hi,
    const unsigned short* __restrict__ Wtq_lo,
    const float* __restrict__ b_qf,
    const float* __restrict__ gate_i, const float* __restrict__ qc_i,
    float* __restrict__ query_o)
{
    __shared__ unsigned short Ah[32 * QP];
    __shared__ unsigned short Al[32 * QP];
    const int tid = threadIdx.x;
    const int lane = tid & 63, wave = tid >> 6;
    const int fp0 = blockIdx.x << 5;

    for (int pp = 0; pp < 8; ++pp) {
        const int p = (wave << 3) + pp;
        const float* src = fine + (size_t)(fp0 + p) * 256;
        const int c0 = lane * 4;
        const float4 x = ntload4(src + c0);
        float s = (x.x + x.y) + (x.z + x.w);
        float sq = x.x*x.x + x.y*x.y + x.z*x.z + x.w*x.w;
        s = wave_sum(s); sq = wave_sum(sq);
        const float mean = s * (1.0f / 256.0f);
        const float var  = sq * (1.0f / 256.0f) - mean * mean;
        const float inv  = rsqrtf(var + 1e-3f);
        const float4 g = *(const float4*)(ln_g + c0);
        const float4 h = *(const float4*)(ln_b + c0);
        float y[4];
        y[0] = (x.x - mean) * inv * g.x + h.x;
        y[1] = (x.y - mean) * inv * g.y + h.y;
        y[2] = (x.z - mean) * inv * g.z + h.z;
        y[3] = (x.w - mean) * inv * g.w + h.w;
        unsigned short* ah = Ah + p * QP;
        unsigned short* al = Al + p * QP;
#pragma unroll
        for (int j = 0; j < 4; ++j) {
            const unsigned short hh = f2bf(y[j]);
            ah[c0 + j] = hh;
            al[c0 + j] = f2bf(y[j] - bf2f(hh));
        }
    }
    __syncthreads();

    const int lrow = lane & 15, lk = (lane >> 4) * 8;
    f32x4 acc[2];
    acc[0] = (f32x4){0.f, 0.f, 0.f, 0.f};
    acc[1] = (f32x4){0.f, 0.f, 0.f, 0.f};

    const unsigned short* Bh = Wtq_hi + (size_t)(wave * 16 + lrow) * 256 + lk;
    const unsigned short* Bl = Wtq_lo + (size_t)(wave * 16 + lrow) * 256 + lk;
    bf16x8 pbh[2], pbl[2];
#pragma unroll
    for (int i = 0; i < 2; ++i) {
        pbh[i] = *(const bf16x8*)(Bh + i * 32);
        pbl[i] = *(const bf16x8*)(Bl + i * 32);
    }

#pragma unroll
    for (int kk = 0; kk < 8; ++kk) {
        const int cur = kk & 1;
        const bf16x8 bh = pbh[cur], bl = pbl[cur];
        if (kk < 6) {
            pbh[cur] = *(const bf16x8*)(Bh + (kk + 2) * 32);
            pbl[cur] = *(const bf16x8*)(Bl + (kk + 2) * 32);
        }
#pragma unroll
        for (int mf = 0; mf < 2; ++mf) {
            const bf16x8 ah = *(const bf16x8*)&Ah[(mf * 16 + lrow) * QP + kk * 32 + lk];
            const bf16x8 al = *(const bf16x8*)&Al[(mf * 16 + lrow) * QP + kk * 32 + lk];
            acc[mf] = __builtin_amdgcn_mfma_f32_16x16x32_bf16(ah, bh, acc[mf], 0, 0, 0);
            acc[mf] = __builtin_amdgcn_mfma_f32_16x16x32_bf16(al, bh, acc[mf], 0, 0, 0);
            acc[mf] = __builtin_amdgcn_mfma_f32_16x16x32_bf16(ah, bl, acc[mf], 0, 0, 0);
        }
    }

    const int n = wave * 16 + (lane & 15);
    const float bias = b_qf[n];
    const int rbase = (lane >> 4) * 4;
#pragma unroll
    for (int mf = 0; mf < 2; ++mf) {
#pragma unroll
        for (int r = 0; r < 4; ++r) {
            const int m = mf * 16 + rbase + r;
            const int fp = fp0 + m;
            const int wx = fp & 127, h = (fp >> 7) & 127, b2 = fp >> 14;
            const int ci = ((b2 << 6) + (h >> 1)) * 64 + (wx >> 1);
            const float gt = gate_i[ci];
            const float qcv = qc_i[(size_t)ci * 64 + n];
            ntstore(query_o + (size_t)fp * 64 + n, (acc[mf][r] + bias) * gt + qcv * (1.0f - gt));
        }
    }
}

// ---------------- Kernel 3: MFMA 5x5 local attention -----------------------
#define LDS_K_HI 0
#define LDS_K_LO 4096
#define LDS_VT   8192
#define LDS_ATT  26624
__global__ __launch_bounds__(256) void k_attn_mfma(
    const float* __restrict__ query, const float* __restrict__ key,
    const float* __restrict__ value, float* __restrict__ out)
{
    __shared__ unsigned short LDS[30720];
    const int tid = threadIdx.x;
    const int lane = tid & 63, wave = tid >> 6;
    const int m16 = lane & 15, g4 = lane >> 4;
    const int blk = blockIdx.x;
    const int bx = blk & 15, by = (blk >> 4) & 15, bb = blk >> 8;
    const int cy0 = by << 2, cx0 = bx << 2;

    {
        const int tau = lane;
        const int chunk = wave;
        const int cy = cy0 - 2 + (tau >> 3), cx = cx0 - 2 + (tau & 7);
        float v[16];
        if ((unsigned)cy < 64u && (unsigned)cx < 64u) {
            const float* src = key + ((size_t)(((bb << 6) + cy) << 6) + cx) * 64 + chunk * 16;
#pragma unroll
            for (int i = 0; i < 4; ++i) {
                const float4 x = *(const float4*)(src + i * 4);
                v[i*4+0]=x.x; v[i*4+1]=x.y; v[i*4+2]=x.z; v[i*4+3]=x.w;
            }
        } else {
#pragma unroll
            for (int i = 0; i < 16; ++i) v[i] = 0.f;
        }
        unsigned hi[8] __attribute__((aligned(16)));
        unsigned lo[8] __attribute__((aligned(16)));
#pragma unroll
        for (int i = 0; i < 8; ++i) {
            const unsigned short h0 = f2bf(v[2*i]), h1 = f2bf(v[2*i+1]);
            hi[i] = (unsigned)h0 | ((unsigned)h1 << 16);
            const unsigned short l0 = f2bf(v[2*i] - bf2f(h0));
            const unsigned short l1 = f2bf(v[2*i+1] - bf2f(h1));
            lo[i] = (unsigned)l0 | ((unsigned)l1 << 16);
        }
#pragma unroll
        for (int g = 0; g < 2; ++g) {
            const int G = chunk * 2 + g;
            const int a = tau * 64 + ((G ^ (tau & 7)) * 8);
            *(uint4*)&LDS[LDS_K_HI + a] = *(const uint4*)&hi[g*4];
            *(uint4*)&LDS[LDS_K_LO + a] = *(const uint4*)&lo[g*4];
        }
    }

    {
        const int p2 = lane & 31;
        const int pos0 = p2 * 2;
        const int cy = cy0 - 2 + (pos0 >> 3);
        const int cx = cx0 - 2 + (pos0 & 7);
        const bool ok0 = ((unsigned)cy < 64u) && ((unsigned)cx < 64u);
        const bool ok1 = ((unsigned)cy < 64u) && ((unsigned)(cx + 1) < 64u);
        const size_t base0 = ((size_t)(((bb << 6) + cy) << 6) + cx) * 256;
        const int chbase = wave * 64 + (lane >> 5) * 4;
#pragma unroll
        for (int it = 0; it < 8; ++it) {
            const int ch = chbase + it * 8;
            const float4 a = ok0 ? *(const float4*)(value + base0 + ch)
                                 : make_float4(0.f, 0.f, 0.f, 0.f);
            const float4 b = ok1 ? *(const float4*)(value + base0 + 256 + ch)
                                 : make_float4(0.f, 0.f, 0.f, 0.f);
            const float av[4] = {a.x, a.y, a.z, a.w};
            const float bv[4] = {b.x, b.y, b.z, b.w};
#pragma unroll
            for (int i = 0; i < 4; ++i) {
                const unsigned w = (unsigned)f2bf(av[i]) | ((unsigned)f2bf(bv[i]) << 16);
                *(unsigned*)&LDS[LDS_VT + (ch + i) * 72 + pos0] = w;
            }
        }
    }

    {
        const uint4 z = {0u, 0u, 0u, 0u};
        *(uint4*)&LDS[LDS_ATT + tid * 8] = z;
        *(uint4*)&LDS[LDS_ATT + 2048 + tid * 8] = z;
    }

    const int fybase = (by << 3) + (wave << 1);
    bf16x8 qh[2], ql[2];
    {
        const int fy = fybase + (m16 >> 3);
        const int fx = (bx << 3) + (m16 & 7);
        const float* qsrc = query + ((size_t)(((bb << 7) + fy) << 7) + fx) * 64;
#pragma unroll
        for (int kf = 0; kf < 2; ++kf) {
            float q8[8];
#pragma unroll
            for (int i = 0; i < 2; ++i) {
                const float4 x = *(const float4*)(qsrc + kf * 32 + g4 * 8 + i * 4);
                q8[i*4+0]=x.x; q8[i*4+1]=x.y; q8[i*4+2]=x.z; q8[i*4+3]=x.w;
            }
            union { unsigned u[4]; bf16x8 b; } uh, ul;
#pragma unroll
            for (int i = 0; i < 4; ++i) {
                const unsigned short h0 = f2bf(q8[2*i]), h1 = f2bf(q8[2*i+1]);
                uh.u[i] = (unsigned)h0 | ((unsigned)h1 << 16);
                const unsigned short l0 = f2bf(q8[2*i] - bf2f(h0));
                const unsigned short l1 = f2bf(q8[2*i+1] - bf2f(h1));
                ul.u[i] = (unsigned)l0 | ((unsigned)l1 << 16);
            }
            qh[kf] = uh.b; ql[kf] = ul.b;
        }
    }

    __syncthreads();

    f32x4 sc[3];
#pragma unroll
    for (int nf = 0; nf < 3; ++nf) sc[nf] = (f32x4){0.f, 0.f, 0.f, 0.f};
#pragma unroll
    for (int nf = 0; nf < 3; ++nf) {
        const int row = 8 * wave + nf * 16 + m16;
#pragma unroll
        for (int kf = 0; kf < 2; ++kf) {
            const int G = kf * 4 + g4;
            const int a = row * 64 + ((G ^ (m16 & 7)) * 8);
            const bf16x8 bh = *(const bf16x8*)&LDS[LDS_K_HI + a];
            const bf16x8 bl = *(const bf16x8*)&LDS[LDS_K_LO + a];
            sc[nf] = __builtin_amdgcn_mfma_f32_16x16x32_bf16(qh[kf], bh, sc[nf], 0, 0, 0);
            sc[nf] = __builtin_amdgcn_mfma_f32_16x16x32_bf16(ql[kf], bh, sc[nf], 0, 0, 0);
            sc[nf] = __builtin_amdgcn_mfma_f32_16x16x32_bf16(qh[kf], bl, sc[nf], 0, 0, 0);
        }
    }

    float e[3][4];
    float rinv[4];
#pragma unroll
    for (int r = 0; r < 4; ++r) {
        const int m = 4 * g4 + r;
        const int j = (m & 7) >> 1;
        float mr = -1e30f;
#pragma unroll
        for (int nf = 0; nf < 3; ++nf) {
            const int tf = nf * 16 + m16;
            const int tc = tf & 7;
            const bool c = (tf < 40) && (tc >= j) && (tc <= j + 4);
            e[nf][r] = c ? sc[nf][r] : -1e30f;
            mr = fmaxf(mr, e[nf][r]);
        }
#pragma unroll
        for (int msk = 1; msk < 16; msk <<= 1) mr = fmaxf(mr, __shfl_xor(mr, msk, 64));
        float s = 0.f;
#pragma unroll
        for (int nf = 0; nf < 3; ++nf) {
            const float ev = (e[nf][r] > -1e29f) ? __expf(e[nf][r] - mr) : 0.f;
            e[nf][r] = ev; s += ev;
        }
#pragma unroll
        for (int msk = 1; msk < 16; msk <<= 1) s += __shfl_xor(s, msk, 64);
        rinv[r] = 1.0f / s;
    }

#pragma unroll
    for (int nf = 0; nf < 3; ++nf) {
        const int t = 8 * wave + nf * 16 + m16;
        if (t < 64) {
#pragma unroll
            for (int r = 0; r < 4; ++r) {
                const int prow = wave * 16 + 4 * g4 + r;
                const int a = prow * 64 + (((t >> 3) ^ (prow & 7)) * 8) + (t & 7);
                LDS[LDS_ATT + a] = f2bf(e[nf][r] * rinv[r]);
            }
        }
    }

    bf16x8 af[2];
#pragma unroll
    for (int kf = 0; kf < 2; ++kf) {
        const int row = wave * 16 + m16;
        const int G = kf * 4 + g4;
        af[kf] = *(const bf16x8*)&LDS[LDS_ATT + row * 64 + ((G ^ (m16 & 7)) * 8)];
    }
    f32x4 ao[16];
#pragma unroll
    for (int nf = 0; nf < 16; ++nf) ao[nf] = (f32x4){0.f, 0.f, 0.f, 0.f};
#pragma unroll
    for (int nf = 0; nf < 16; ++nf) {
        const int ch = nf * 16 + m16;
#pragma unroll
        for (int kf = 0; kf < 2; ++kf) {
            const bf16x8 b = *(const bf16x8*)&LDS[LDS_VT + ch * 72 + kf * 32 + g4 * 8];
            ao[nf] = __builtin_amdgcn_mfma_f32_16x16x32_bf16(af[kf], b, ao[nf], 0, 0, 0);
        }
    }

#pragma unroll
    for (int r = 0; r < 4; ++r) {
        const int m = 4 * g4 + r;
        const int fy = fybase + (m >> 3);
        const int fx = (bx << 3) + (m & 7);
        float* op = out + ((size_t)(((bb << 7) + fy) << 7) + fx) * 256 + m16;
#pragma unroll
        for (int nf = 0; nf < 16; ++nf)
            ntstore(op + nf * 16, ao[nf][r]);
    }
}

// ---------------- launch ----------------
extern "C" void kernel_launch(void* const* d_in, const int* in_sizes, int n_in,
                              void* d_out, int out_size, void* d_ws, size_t ws_size,
                              hipStream_t stream)
{
    const float* fine   = (const float*)d_in[0];
    const float* coarse = (const float*)d_in[1];
    const float* ln_f_g = (const float*)d_in[2];
    const float* ln_f_b = (const float*)d_in[3];
    const float* ln_c_g = (const float*)d_in[4];
    const float* ln_c_b = (const float*)d_in[5];
    const float* w_gate = (const float*)d_in[6];
    const float* b_gate = (const float*)d_in[7];
    const float* w_qf   = (const float*)d_in[8];
    const float* b_qf   = (const float*)d_in[9];
    const float* w_qc   = (const float*)d_in[10];
    const float* b_qc   = (const float*)d_in[11];
    const float* w_k    = (const float*)d_in[12];
    const float* b_k    = (const float*)d_in[13];
    const float* w_v    = (const float*)d_in[14];
    const float* b_v    = (const float*)d_in[15];
    float* out = (float*)d_out;

    float* ws   = (float*)d_ws;
    float* gate = ws;                                   // 16384
    float* qc   = gate + 16384;                         // 16384*64
    float* keyb = qc   + (size_t)16384 * 64;            // 16384*64
    float* valb = keyb + (size_t)16384 * 64;            // 16384*256
    float* qry  = valb + (size_t)16384 * 256;           // 65536*64
    unsigned short* Wt_hi  = (unsigned short*)(qry + (size_t)65536 * 64);
    unsigned short* Wt_lo  = Wt_hi  + (size_t)384 * 512;
    unsigned short* Wtq_hi = Wt_lo  + (size_t)384 * 512;
    unsigned short* Wtq_lo = Wtq_hi + (size_t)64 * 256;

    k_wconv<<<52, 256, 0, stream>>>(w_qc, w_k, w_v, w_qf, Wt_hi, Wt_lo, Wtq_hi, Wtq_lo);
    k_coarse_fused<<<512, 512, 0, stream>>>(coarse, ln_c_g, ln_c_b, w_gate, b_gate,
                                            Wt_hi, Wt_lo, b_qc, b_k, b_v,
                                            gate, qc, keyb, valb);
    k_query_fused<<<2048, 256, 0, stream>>>(fine, ln_f_g, ln_f_b, Wtq_hi, Wtq_lo, b_qf,
                                            gate, qc, qry);
    k_attn_mfma<<<1024, 256, 0, stream>>>(qry, keyb, valb, out);
}

// Round 8
// 85.837 us; speedup vs baseline: 1.3283x; 1.3283x over previous
//
#include <hip/hip_runtime.h>
#include <math.h>

typedef __bf16 bf16x8 __attribute__((ext_vector_type(8)));
typedef float  f32x4  __attribute__((ext_vector_type(4)));
typedef float  vf4    __attribute__((ext_vector_type(4)));

__device__ __forceinline__ float wave_sum(float v) {
#pragma unroll
    for (int m = 1; m < 64; m <<= 1) v += __shfl_xor(v, m, 64);
    return v;
}

__device__ __forceinline__ unsigned short f2bf(float f) {
    union { float f; unsigned int u; } x; x.f = f;
    unsigned int u = x.u;
    u += 0x7fffu + ((u >> 16) & 1u);   // round-to-nearest-even
    return (unsigned short)(u >> 16);
}
__device__ __forceinline__ float bf2f(unsigned short h) {
    union { unsigned int u; float f; } x; x.u = ((unsigned int)h) << 16;
    return x.f;
}

// NT loads only for read-once streams (coarse/fine pixels)
__device__ __forceinline__ float4 ntload4(const float* p) {
    const vf4 v = __builtin_nontemporal_load((const vf4*)p);
    return make_float4(v.x, v.y, v.z, v.w);
}

// ------- weight convert to MFMA fragment-linear layout ---------------------
// Coarse: 24 n-tiles (0..7 split qc/key, 8..23 value), 16 kk, 64 lanes, 8 bf16.
//   WfragC_hi[((nf*16+kk)*64+lane)*8 + j] = bf16( W[n = nf*16+(lane&15)]
//                                                  [k = kk*32+(lane>>4)*8+j] )
//   WfragC_lo: same index, only nf<8 (residual for split-bf16).
// Query: 4 n-tiles, 8 kk -> WfragQ_hi/lo[((nf*8+kk)*64+lane)*8 + j].
__global__ __launch_bounds__(256) void k_wconv(
    const float* __restrict__ w_qc, const float* __restrict__ w_k,
    const float* __restrict__ w_v, const float* __restrict__ w_qf,
    unsigned short* __restrict__ WfragC_hi, unsigned short* __restrict__ WfragC_lo,
    unsigned short* __restrict__ WfragQ_hi, unsigned short* __restrict__ WfragQ_lo)
{
    const int t = blockIdx.x * 256 + threadIdx.x;
    if (t < 24576) {                       // coarse frags
        const int lane = t & 63, kk = (t >> 6) & 15, nf = t >> 10;
        const int n  = nf * 16 + (lane & 15);
        const int k0 = kk * 32 + (lane >> 4) * 8;
        const float* src; int col, w;
        if (n < 64)       { src = w_qc; col = n;       w = 64;  }
        else if (n < 128) { src = w_k;  col = n - 64;  w = 64;  }
        else              { src = w_v;  col = n - 128; w = 256; }
        unsigned hi[4], lo[4];
#pragma unroll
        for (int i = 0; i < 4; ++i) {
            const float v0 = src[(size_t)(k0 + 2*i)     * w + col];
            const float v1 = src[(size_t)(k0 + 2*i + 1) * w + col];
            const unsigned short h0 = f2bf(v0), h1 = f2bf(v1);
            hi[i] = (unsigned)h0 | ((unsigned)h1 << 16);
            lo[i] = (unsigned)f2bf(v0 - bf2f(h0)) | ((unsigned)f2bf(v1 - bf2f(h1)) << 16);
        }
        *(uint4*)&WfragC_hi[(size_t)t * 8] = *(const uint4*)hi;
        if (nf < 8) *(uint4*)&WfragC_lo[(size_t)t * 8] = *(const uint4*)lo;
    } else if (t < 24576 + 2048) {         // query frags
        const int t2 = t - 24576;
        const int lane = t2 & 63, kk = (t2 >> 6) & 7, nf = t2 >> 9;
        const int n  = nf * 16 + (lane & 15);
        const int k0 = kk * 32 + (lane >> 4) * 8;
        unsigned hi[4], lo[4];
#pragma unroll
        for (int i = 0; i < 4; ++i) {
            const float v0 = w_qf[(size_t)(k0 + 2*i)     * 64 + n];
            const float v1 = w_qf[(size_t)(k0 + 2*i + 1) * 64 + n];
            const unsigned short h0 = f2bf(v0), h1 = f2bf(v1);
            hi[i] = (unsigned)h0 | ((unsigned)h1 << 16);
            lo[i] = (unsigned)f2bf(v0 - bf2f(h0)) | ((unsigned)f2bf(v1 - bf2f(h1)) << 16);
        }
        *(uint4*)&WfragQ_hi[(size_t)t2 * 8] = *(const uint4*)hi;
        *(uint4*)&WfragQ_lo[(size_t)t2 * 8] = *(const uint4*)lo;
    }
}

// ---------------- Kernel 1: fused coarse LN + gate + MFMA GEMM -------------
// 512 threads (8 waves), M=32 px/block, K=512, N=384.
// Per wave: split tile nf=wave (3 MFMA) + value tiles nf=8+2w, 9+2w.
#define AP 520
__global__ __launch_bounds__(512) void k_coarse_fused(
    const float* __restrict__ coarse,
    const float* __restrict__ ln_g, const float* __restrict__ ln_b,
    const float* __restrict__ w_gate, const float* __restrict__ b_gate,
    const unsigned short* __restrict__ WfragC_hi,
    const unsigned short* __restrict__ WfragC_lo,
    const float* __restrict__ b_qc, const float* __restrict__ b_k,
    const float* __restrict__ b_v,
    float* __restrict__ gate_o, float* __restrict__ qc_o,
    float* __restrict__ key_o, float* __restrict__ val_o)
{
    __shared__ unsigned short Ah[32 * AP];   // 33280 B
    __shared__ unsigned short Al[32 * AP];   // 33280 B -> 2 blocks/CU
    const int tid = threadIdx.x;
    const int lane = tid & 63, wave = tid >> 6;
    const int ci0 = blockIdx.x << 5;

    // --- LN phase (NT loads: read-once stream) ---
    for (int pp = 0; pp < 4; ++pp) {
        const int p = (wave << 2) + pp;
        const float* src = coarse + (size_t)(ci0 + p) * 512;
        const int c0 = lane * 4, c1 = 256 + lane * 4;
        const float4 x0 = ntload4(src + c0);
        const float4 x1 = ntload4(src + c1);
        float s = (x0.x + x0.y) + (x0.z + x0.w) + (x1.x + x1.y) + (x1.z + x1.w);
        float sq = x0.x*x0.x + x0.y*x0.y + x0.z*x0.z + x0.w*x0.w
                 + x1.x*x1.x + x1.y*x1.y + x1.z*x1.z + x1.w*x1.w;
        s = wave_sum(s); sq = wave_sum(sq);
        const float mean = s * (1.0f / 512.0f);
        const float var  = sq * (1.0f / 512.0f) - mean * mean;
        const float inv  = rsqrtf(var + 1e-3f);
        const float4 g0 = *(const float4*)(ln_g + c0), g1 = *(const float4*)(ln_g + c1);
        const float4 h0 = *(const float4*)(ln_b + c0), h1 = *(const float4*)(ln_b + c1);
        float y[8];
        y[0] = (x0.x - mean) * inv * g0.x + h0.x;
        y[1] = (x0.y - mean) * inv * g0.y + h0.y;
        y[2] = (x0.z - mean) * inv * g0.z + h0.z;
        y[3] = (x0.w - mean) * inv * g0.w + h0.w;
        y[4] = (x1.x - mean) * inv * g1.x + h1.x;
        y[5] = (x1.y - mean) * inv * g1.y + h1.y;
        y[6] = (x1.z - mean) * inv * g1.z + h1.z;
        y[7] = (x1.w - mean) * inv * g1.w + h1.w;
        unsigned short* ah = Ah + p * AP;
        unsigned short* al = Al + p * AP;
#pragma unroll
        for (int j = 0; j < 8; ++j) {
            const int c = (j < 4) ? (c0 + j) : (c1 + j - 4);
            const unsigned short h = f2bf(y[j]);
            ah[c] = h;
            al[c] = f2bf(y[j] - bf2f(h));
        }
        const float4 wg0 = *(const float4*)(w_gate + c0), wg1 = *(const float4*)(w_gate + c1);
        float gd = y[0]*wg0.x + y[1]*wg0.y + y[2]*wg0.z + y[3]*wg0.w
                 + y[4]*wg1.x + y[5]*wg1.y + y[6]*wg1.z + y[7]*wg1.w;
        gd = wave_sum(gd);
        if (lane == 0) gate_o[ci0 + p] = 1.0f / (1.0f + __expf(-(gd + b_gate[0])));
    }
    __syncthreads();

    // --- GEMM: fragment-linear B loads, each 16B/lane fully coalesced ---
    const int lrow = lane & 15, m16 = lane & 15, lk = (lane >> 4) * 8;
    f32x4 acc_s[2], acc_v[2][2];
#pragma unroll
    for (int i = 0; i < 2; ++i) {
        acc_s[i] = (f32x4){0.f, 0.f, 0.f, 0.f};
        acc_v[i][0] = (f32x4){0.f, 0.f, 0.f, 0.f};
        acc_v[i][1] = (f32x4){0.f, 0.f, 0.f, 0.f};
    }

    // fragment stream bases (advance by 64*8 halves per kk)
    const unsigned short* Fs_h = WfragC_hi + ((size_t)(wave * 16) * 64 + lane) * 8;
    const unsigned short* Fs_l = WfragC_lo + ((size_t)(wave * 16) * 64 + lane) * 8;
    const unsigned short* Fv0  = WfragC_hi + ((size_t)((8 + 2*wave) * 16) * 64 + lane) * 8;
    const unsigned short* Fv1  = WfragC_hi + ((size_t)((9 + 2*wave) * 16) * 64 + lane) * 8;
    const int KSTEP = 64 * 8;   // halves per kk

    // depth-4 register prefetch (fully unrolled -> static indices)
    bf16x8 pbh[4], pbl[4], pv0[4], pv1[4];
#pragma unroll
    for (int i = 0; i < 4; ++i) {
        pbh[i] = *(const bf16x8*)(Fs_h + i * KSTEP);
        pbl[i] = *(const bf16x8*)(Fs_l + i * KSTEP);
        pv0[i] = *(const bf16x8*)(Fv0 + i * KSTEP);
        pv1[i] = *(const bf16x8*)(Fv1 + i * KSTEP);
    }

#pragma unroll
    for (int kk = 0; kk < 16; ++kk) {
        const int cur = kk & 3;
        const bf16x8 bh = pbh[cur], bl = pbl[cur], v0 = pv0[cur], v1 = pv1[cur];
        if (kk < 12) {
            pbh[cur] = *(const bf16x8*)(Fs_h + (kk + 4) * KSTEP);
            pbl[cur] = *(const bf16x8*)(Fs_l + (kk + 4) * KSTEP);
            pv0[cur] = *(const bf16x8*)(Fv0 + (kk + 4) * KSTEP);
            pv1[cur] = *(const bf16x8*)(Fv1 + (kk + 4) * KSTEP);
        }
        bf16x8 ah[2], alo[2];
#pragma unroll
        for (int mf = 0; mf < 2; ++mf) {
            ah[mf]  = *(const bf16x8*)&Ah[(mf * 16 + lrow) * AP + kk * 32 + lk];
            alo[mf] = *(const bf16x8*)&Al[(mf * 16 + lrow) * AP + kk * 32 + lk];
        }
#pragma unroll
        for (int mf = 0; mf < 2; ++mf) {
            acc_s[mf] = __builtin_amdgcn_mfma_f32_16x16x32_bf16(ah[mf],  bh, acc_s[mf], 0, 0, 0);
            acc_s[mf] = __builtin_amdgcn_mfma_f32_16x16x32_bf16(alo[mf], bh, acc_s[mf], 0, 0, 0);
            acc_s[mf] = __builtin_amdgcn_mfma_f32_16x16x32_bf16(ah[mf],  bl, acc_s[mf], 0, 0, 0);
            acc_v[mf][0] = __builtin_amdgcn_mfma_f32_16x16x32_bf16(ah[mf], v0, acc_v[mf][0], 0, 0, 0);
            acc_v[mf][1] = __builtin_amdgcn_mfma_f32_16x16x32_bf16(ah[mf], v1, acc_v[mf][1], 0, 0, 0);
        }
    }

    // --- epilogue (plain stores: consumers want L2 hits) ---
    const int rbase = (lane >> 4) * 4;
    const int ns = wave * 16 + m16;
#pragma unroll
    for (int mf = 0; mf < 2; ++mf) {
#pragma unroll
        for (int r = 0; r < 4; ++r) {
            const int m = mf * 16 + rbase + r;
            const int ci = ci0 + m;
            const float vs = acc_s[mf][r];
            if (ns < 64) qc_o [(size_t)ci * 64 + ns]      = vs + b_qc[ns];
            else         key_o[(size_t)ci * 64 + ns - 64] = vs + b_k[ns - 64];
#pragma unroll
            for (int vv = 0; vv < 2; ++vv) {
                const int ch = wave * 32 + vv * 16 + m16;
                val_o[(size_t)ci * 256 + ch] = acc_v[mf][vv][r] + b_v[ch];
            }
        }
    }
}

// ---------------- Kernel 2: fused fine LN + split-bf16 qf + gating ---------
#define QP 264
__global__ __launch_bounds__(256) void k_query_fused(
    const float* __restrict__ fine,
    const float* __restrict__ ln_g, const float* __restrict__ ln_b,
    const unsigned short* __restrict__ WfragQ_hi,
    const unsigned short* __restrict__ WfragQ_lo,
    const float* __restrict__ b_qf,
    const float* __restrict__ gate_i, const float* __restrict__ qc_i,
    float* __restrict__ query_o)
{
    __shared__ unsigned short Ah[32 * QP];
    __shared__ unsigned short Al[32 * QP];
    const int tid = threadIdx.x;
    const int lane = tid & 63, wave = tid >> 6;
    const int fp0 = blockIdx.x << 5;

    for (int pp = 0; pp < 8; ++pp) {
        const int p = (wave << 3) + pp;
        const float* src = fine + (size_t)(fp0 + p) * 256;
        const int c0 = lane * 4;
        const float4 x = ntload4(src + c0);
        float s = (x.x + x.y) + (x.z + x.w);
        float sq = x.x*x.x + x.y*x.y + x.z*x.z + x.w*x.w;
        s = wave_sum(s); sq = wave_sum(sq);
        const float mean = s * (1.0f / 256.0f);
        const float var  = sq * (1.0f / 256.0f) - mean * mean;
        const float inv  = rsqrtf(var + 1e-3f);
        const float4 g = *(const float4*)(ln_g + c0);
        const float4 h = *(const float4*)(ln_b + c0);
        float y[4];
        y[0] = (x.x - mean) * inv * g.x + h.x;
        y[1] = (x.y - mean) * inv * g.y + h.y;
        y[2] = (x.z - mean) * inv * g.z + h.z;
        y[3] = (x.w - mean) * inv * g.w + h.w;
        unsigned short* ah = Ah + p * QP;
        unsigned short* al = Al + p * QP;
#pragma unroll
        for (int j = 0; j < 4; ++j) {
            const unsigned short hh = f2bf(y[j]);
            ah[c0 + j] = hh;
            al[c0 + j] = f2bf(y[j] - bf2f(hh));
        }
    }
    __syncthreads();

    const int lrow = lane & 15, lk = (lane >> 4) * 8;
    f32x4 acc[2];
    acc[0] = (f32x4){0.f, 0.f, 0.f, 0.f};
    acc[1] = (f32x4){0.f, 0.f, 0.f, 0.f};

    const unsigned short* Fh = WfragQ_hi + ((size_t)(wave * 8) * 64 + lane) * 8;
    const unsigned short* Fl = WfragQ_lo + ((size_t)(wave * 8) * 64 + lane) * 8;
    const int KSTEP = 64 * 8;
    bf16x8 pbh[4], pbl[4];
#pragma unroll
    for (int i = 0; i < 4; ++i) {
        pbh[i] = *(const bf16x8*)(Fh + i * KSTEP);
        pbl[i] = *(const bf16x8*)(Fl + i * KSTEP);
    }

#pragma unroll
    for (int kk = 0; kk < 8; ++kk) {
        const int cur = kk & 3;
        const bf16x8 bh = pbh[cur], bl = pbl[cur];
        if (kk < 4) {
            pbh[cur] = *(const bf16x8*)(Fh + (kk + 4) * KSTEP);
            pbl[cur] = *(const bf16x8*)(Fl + (kk + 4) * KSTEP);
        }
#pragma unroll
        for (int mf = 0; mf < 2; ++mf) {
            const bf16x8 ah = *(const bf16x8*)&Ah[(mf * 16 + lrow) * QP + kk * 32 + lk];
            const bf16x8 al = *(const bf16x8*)&Al[(mf * 16 + lrow) * QP + kk * 32 + lk];
            acc[mf] = __builtin_amdgcn_mfma_f32_16x16x32_bf16(ah, bh, acc[mf], 0, 0, 0);
            acc[mf] = __builtin_amdgcn_mfma_f32_16x16x32_bf16(al, bh, acc[mf], 0, 0, 0);
            acc[mf] = __builtin_amdgcn_mfma_f32_16x16x32_bf16(ah, bl, acc[mf], 0, 0, 0);
        }
    }

    const int n = wave * 16 + (lane & 15);
    const float bias = b_qf[n];
    const int rbase = (lane >> 4) * 4;
#pragma unroll
    for (int mf = 0; mf < 2; ++mf) {
#pragma unroll
        for (int r = 0; r < 4; ++r) {
            const int m = mf * 16 + rbase + r;
            const int fp = fp0 + m;
            const int wx = fp & 127, h = (fp >> 7) & 127, b2 = fp >> 14;
            const int ci = ((b2 << 6) + (h >> 1)) * 64 + (wx >> 1);
            const float gt = gate_i[ci];
            const float qcv = qc_i[(size_t)ci * 64 + n];
            query_o[(size_t)fp * 64 + n] = (acc[mf][r] + bias) * gt + qcv * (1.0f - gt);
        }
    }
}

// ---------------- Kernel 3: MFMA 5x5 local attention -----------------------
#define LDS_K_HI 0
#define LDS_K_LO 4096
#define LDS_VT   8192
#define LDS_ATT  26624
__global__ __launch_bounds__(256) void k_attn_mfma(
    const float* __restrict__ query, const float* __restrict__ key,
    const float* __restrict__ value, float* __restrict__ out)
{
    __shared__ unsigned short LDS[30720];
    const int tid = threadIdx.x;
    const int lane = tid & 63, wave = tid >> 6;
    const int m16 = lane & 15, g4 = lane >> 4;
    const int blk = blockIdx.x;
    const int bx = blk & 15, by = (blk >> 4) & 15, bb = blk >> 8;
    const int cy0 = by << 2, cx0 = bx << 2;

    {
        const int tau = lane;
        const int chunk = wave;
        const int cy = cy0 - 2 + (tau >> 3), cx = cx0 - 2 + (tau & 7);
        float v[16];
        if ((unsigned)cy < 64u && (unsigned)cx < 64u) {
            const float* src = key + ((size_t)(((bb << 6) + cy) << 6) + cx) * 64 + chunk * 16;
#pragma unroll
            for (int i = 0; i < 4; ++i) {
                const float4 x = *(const float4*)(src + i * 4);
                v[i*4+0]=x.x; v[i*4+1]=x.y; v[i*4+2]=x.z; v[i*4+3]=x.w;
            }
        } else {
#pragma unroll
            for (int i = 0; i < 16; ++i) v[i] = 0.f;
        }
        unsigned hi[8] __attribute__((aligned(16)));
        unsigned lo[8] __attribute__((aligned(16)));
#pragma unroll
        for (int i = 0; i < 8; ++i) {
            const unsigned short h0 = f2bf(v[2*i]), h1 = f2bf(v[2*i+1]);
            hi[i] = (unsigned)h0 | ((unsigned)h1 << 16);
            const unsigned short l0 = f2bf(v[2*i] - bf2f(h0));
            const unsigned short l1 = f2bf(v[2*i+1] - bf2f(h1));
            lo[i] = (unsigned)l0 | ((unsigned)l1 << 16);
        }
#pragma unroll
        for (int g = 0; g < 2; ++g) {
            const int G = chunk * 2 + g;
            const int a = tau * 64 + ((G ^ (tau & 7)) * 8);
            *(uint4*)&LDS[LDS_K_HI + a] = *(const uint4*)&hi[g*4];
            *(uint4*)&LDS[LDS_K_LO + a] = *(const uint4*)&lo[g*4];
        }
    }

    {
        const int p2 = lane & 31;
        const int pos0 = p2 * 2;
        const int cy = cy0 - 2 + (pos0 >> 3);
        const int cx = cx0 - 2 + (pos0 & 7);
        const bool ok0 = ((unsigned)cy < 64u) && ((unsigned)cx < 64u);
        const bool ok1 = ((unsigned)cy < 64u) && ((unsigned)(cx + 1) < 64u);
        const size_t base0 = ((size_t)(((bb << 6) + cy) << 6) + cx) * 256;
        const int chbase = wave * 64 + (lane >> 5) * 4;
#pragma unroll
        for (int it = 0; it < 8; ++it) {
            const int ch = chbase + it * 8;
            const float4 a = ok0 ? *(const float4*)(value + base0 + ch)
                                 : make_float4(0.f, 0.f, 0.f, 0.f);
            const float4 b = ok1 ? *(const float4*)(value + base0 + 256 + ch)
                                 : make_float4(0.f, 0.f, 0.f, 0.f);
            const float av[4] = {a.x, a.y, a.z, a.w};
            const float bv[4] = {b.x, b.y, b.z, b.w};
#pragma unroll
            for (int i = 0; i < 4; ++i) {
                const unsigned w = (unsigned)f2bf(av[i]) | ((unsigned)f2bf(bv[i]) << 16);
                *(unsigned*)&LDS[LDS_VT + (ch + i) * 72 + pos0] = w;
            }
        }
    }

    {
        const uint4 z = {0u, 0u, 0u, 0u};
        *(uint4*)&LDS[LDS_ATT + tid * 8] = z;
        *(uint4*)&LDS[LDS_ATT + 2048 + tid * 8] = z;
    }

    const int fybase = (by << 3) + (wave << 1);
    bf16x8 qh[2], ql[2];
    {
        const int fy = fybase + (m16 >> 3);
        const int fx = (bx << 3) + (m16 & 7);
        const float* qsrc = query + ((size_t)(((bb << 7) + fy) << 7) + fx) * 64;
#pragma unroll
        for (int kf = 0; kf < 2; ++kf) {
            float q8[8];
#pragma unroll
            for (int i = 0; i < 2; ++i) {
                const float4 x = *(const float4*)(qsrc + kf * 32 + g4 * 8 + i * 4);
                q8[i*4+0]=x.x; q8[i*4+1]=x.y; q8[i*4+2]=x.z; q8[i*4+3]=x.w;
            }
            union { unsigned u[4]; bf16x8 b; } uh, ul;
#pragma unroll
            for (int i = 0; i < 4; ++i) {
                const unsigned short h0 = f2bf(q8[2*i]), h1 = f2bf(q8[2*i+1]);
                uh.u[i] = (unsigned)h0 | ((unsigned)h1 << 16);
                const unsigned short l0 = f2bf(q8[2*i] - bf2f(h0));
                const unsigned short l1 = f2bf(q8[2*i+1] - bf2f(h1));
                ul.u[i] = (unsigned)l0 | ((unsigned)l1 << 16);
            }
            qh[kf] = uh.b; ql[kf] = ul.b;
        }
    }

    __syncthreads();

    f32x4 sc[3];
#pragma unroll
    for (int nf = 0; nf < 3; ++nf) sc[nf] = (f32x4){0.f, 0.f, 0.f, 0.f};
#pragma unroll
    for (int nf = 0; nf < 3; ++nf) {
        const int row = 8 * wave + nf * 16 + m16;
#pragma unroll
        for (int kf = 0; kf < 2; ++kf) {
            const int G = kf * 4 + g4;
            const int a = row * 64 + ((G ^ (m16 & 7)) * 8);
            const bf16x8 bh = *(const bf16x8*)&LDS[LDS_K_HI + a];
            const bf16x8 bl = *(const bf16x8*)&LDS[LDS_K_LO + a];
            sc[nf] = __builtin_amdgcn_mfma_f32_16x16x32_bf16(qh[kf], bh, sc[nf], 0, 0, 0);
            sc[nf] = __builtin_amdgcn_mfma_f32_16x16x32_bf16(ql[kf], bh, sc[nf], 0, 0, 0);
            sc[nf] = __builtin_amdgcn_mfma_f32_16x16x32_bf16(qh[kf], bl, sc[nf], 0, 0, 0);
        }
    }

    float e[3][4];
    float rinv[4];
#pragma unroll
    for (int r = 0; r < 4; ++r) {
        const int m = 4 * g4 + r;
        const int j = (m & 7) >> 1;
        float mr = -1e30f;
#pragma unroll
        for (int nf = 0; nf < 3; ++nf) {
            const int tf = nf * 16 + m16;
            const int tc = tf & 7;
            const bool c = (tf < 40) && (tc >= j) && (tc <= j + 4);
            e[nf][r] = c ? sc[nf][r] : -1e30f;
            mr = fmaxf(mr, e[nf][r]);
        }
#pragma unroll
        for (int msk = 1; msk < 16; msk <<= 1) mr = fmaxf(mr, __shfl_xor(mr, msk, 64));
        float s = 0.f;
#pragma unroll
        for (int nf = 0; nf < 3; ++nf) {
            const float ev = (e[nf][r] > -1e29f) ? __expf(e[nf][r] - mr) : 0.f;
            e[nf][r] = ev; s += ev;
        }
#pragma unroll
        for (int msk = 1; msk < 16; msk <<= 1) s += __shfl_xor(s, msk, 64);
        rinv[r] = 1.0f / s;
    }

#pragma unroll
    for (int nf = 0; nf < 3; ++nf) {
        const int t = 8 * wave + nf * 16 + m16;
        if (t < 64) {
#pragma unroll
            for (int r = 0; r < 4; ++r) {
                const int prow = wave * 16 + 4 * g4 + r;
                const int a = prow * 64 + (((t >> 3) ^ (prow & 7)) * 8) + (t & 7);
                LDS[LDS_ATT + a] = f2bf(e[nf][r] * rinv[r]);
            }
        }
    }

    bf16x8 af[2];
#pragma unroll
    for (int kf = 0; kf < 2; ++kf) {
        const int row = wave * 16 + m16;
        const int G = kf * 4 + g4;
        af[kf] = *(const bf16x8*)&LDS[LDS_ATT + row * 64 + ((G ^ (m16 & 7)) * 8)];
    }
    f32x4 ao[16];
#pragma unroll
    for (int nf = 0; nf < 16; ++nf) ao[nf] = (f32x4){0.f, 0.f, 0.f, 0.f};
#pragma unroll
    for (int nf = 0; nf < 16; ++nf) {
        const int ch = nf * 16 + m16;
#pragma unroll
        for (int kf = 0; kf < 2; ++kf) {
            const bf16x8 b = *(const bf16x8*)&LDS[LDS_VT + ch * 72 + kf * 32 + g4 * 8];
            ao[nf] = __builtin_amdgcn_mfma_f32_16x16x32_bf16(af[kf], b, ao[nf], 0, 0, 0);
        }
    }

#pragma unroll
    for (int r = 0; r < 4; ++r) {
        const int m = 4 * g4 + r;
        const int fy = fybase + (m >> 3);
        const int fx = (bx << 3) + (m & 7);
        float* op = out + ((size_t)(((bb << 7) + fy) << 7) + fx) * 256 + m16;
#pragma unroll
        for (int nf = 0; nf < 16; ++nf)
            op[nf * 16] = ao[nf][r];
    }
}

// ---------------- launch ----------------
extern "C" void kernel_launch(void* const* d_in, const int* in_sizes, int n_in,
                              void* d_out, int out_size, void* d_ws, size_t ws_size,
                              hipStream_t stream)
{
    const float* fine   = (const float*)d_in[0];
    const float* coarse = (const float*)d_in[1];
    const float* ln_f_g = (const float*)d_in[2];
    const float* ln_f_b = (const float*)d_in[3];
    const float* ln_c_g = (const float*)d_in[4];
    const float* ln_c_b = (const float*)d_in[5];
    const float* w_gate = (const float*)d_in[6];
    const float* b_gate = (const float*)d_in[7];
    const float* w_qf   = (const float*)d_in[8];
    const float* b_qf   = (const float*)d_in[9];
    const float* w_qc   = (const float*)d_in[10];
    const float* b_qc   = (const float*)d_in[11];
    const float* w_k    = (const float*)d_in[12];
    const float* b_k    = (const float*)d_in[13];
    const float* w_v    = (const float*)d_in[14];
    const float* b_v    = (const float*)d_in[15];
    float* out = (float*)d_out;

    float* ws   = (float*)d_ws;
    float* gate = ws;                                   // 16384
    float* qc   = gate + 16384;                         // 16384*64
    float* keyb = qc   + (size_t)16384 * 64;            // 16384*64
    float* valb = keyb + (size_t)16384 * 64;            // 16384*256
    float* qry  = valb + (size_t)16384 * 256;           // 65536*64
    unsigned short* WfragC_hi = (unsigned short*)(qry + (size_t)65536 * 64); // 24576*8
    unsigned short* WfragC_lo = WfragC_hi + (size_t)24576 * 8;               // 8192*8
    unsigned short* WfragQ_hi = WfragC_lo + (size_t)8192 * 8;                // 2048*8
    unsigned short* WfragQ_lo = WfragQ_hi + (size_t)2048 * 8;                // 2048*8

    k_wconv<<<104, 256, 0, stream>>>(w_qc, w_k, w_v, w_qf,
                                     WfragC_hi, WfragC_lo, WfragQ_hi, WfragQ_lo);
    k_coarse_fused<<<512, 512, 0, stream>>>(coarse, ln_c_g, ln_c_b, w_gate, b_gate,
                                            WfragC_hi, WfragC_lo, b_qc, b_k, b_v,
                                            gate, qc, keyb, valb);
    k_query_fused<<<2048, 256, 0, stream>>>(fine, ln_f_g, ln_f_b, WfragQ_hi, WfragQ_lo, b_qf,
                                            gate, qc, qry);
    k_attn_mfma<<<1024, 256, 0, stream>>>(qry, keyb, valb, out);
}